// Round 5
// baseline (164.350 us; speedup 1.0000x reference)
//
#include <hip/hip_runtime.h>
#include <stdint.h>

#define M_DIM 4096
#define K_DIM 256

typedef unsigned short us;
typedef __attribute__((ext_vector_type(8))) short bf16x8;
typedef __attribute__((ext_vector_type(4))) float f32x4;

static __device__ __forceinline__ float bf2f(unsigned int u){
  unsigned int x = u << 16; float f;
  __builtin_memcpy(&f, &x, 4); return f;
}
static __device__ __forceinline__ us f2bf(float f){
  unsigned int x; __builtin_memcpy(&x, &f, 4);
  unsigned int r = x + 0x7fffu + ((x >> 16) & 1u);
  return (us)(r >> 16);
}
static __device__ __forceinline__ void gld16(const void* g, void* l){
  __builtin_amdgcn_global_load_lds(
      (const __attribute__((address_space(1))) unsigned int*)g,
      (__attribute__((address_space(3))) unsigned int*)l, 16, 0, 0);
}

// ---- transpose+cast: [b,256,4096] f32 -> [b,4096,256] bf16, both fmaps one launch --
__global__ void k_transpose_cast(const float* __restrict__ f1,
                                 const float* __restrict__ f2,
                                 us* __restrict__ A, us* __restrict__ B0){
  __shared__ float lds[64][65];
  int z = blockIdx.z;           // 0..3 : b = z&1, which = z>>1
  int b = z & 1, which = z >> 1;
  const float* in = which ? f2 : f1;
  us* out = which ? B0 : A;
  float scale = which ? 1.0f : 0.0625f;   // fold 1/sqrt(256) into A
  int c0 = blockIdx.y * 64, m0 = blockIdx.x * 64;
  const float* ib = in + (size_t)b * K_DIM * M_DIM;
  us* ob = out + (size_t)b * M_DIM * K_DIM;
  int t = threadIdx.x, r = t >> 6, j = t & 63;
#pragma unroll
  for (int k = 0; k < 16; k++)
    lds[r + k*4][j] = ib[(size_t)(c0 + r + k*4) * M_DIM + m0 + j];
  __syncthreads();
#pragma unroll
  for (int k = 0; k < 16; k++)
    ob[(size_t)(m0 + r + k*4) * K_DIM + c0 + j] = f2bf(lds[j][r + k*4] * scale);
}

// ---- pools: B1 (2x2), B2 (4x4), B3 (8x8) all directly from B0, one launch ----------
__global__ void k_pool_all(const us* __restrict__ B0, us* __restrict__ B1,
                           us* __restrict__ B2, us* __restrict__ B3){
  int bid = blockIdx.x;
  us* dst; int wd, f;
  if (bid < 512)      { dst = B1; wd = 32; f = 2; }
  else if (bid < 640) { bid -= 512; dst = B2; wd = 16; f = 4; }
  else                { bid -= 640; dst = B3; wd = 8;  f = 8; }
  int t = threadIdx.x;
  int idx = bid * 4 + (t >> 6);
  int l = t & 63;
  int per = wd * wd;
  int b = idx / per, rem = idx - b * per;
  int y = rem / wd, x = rem - y * wd;
  const us* sb = B0 + (size_t)b * 4096 * K_DIM;
  float s0 = 0, s1 = 0, s2 = 0, s3 = 0;
  for (int dy = 0; dy < f; dy++)
    for (int dx = 0; dx < f; dx++){
      size_t off = ((size_t)(f*y + dy) * 64 + (f*x + dx)) * K_DIM + l * 4;
      uint2 v = *(const uint2*)(sb + off);
      s0 += bf2f(v.x & 0xffff); s1 += bf2f(v.x >> 16);
      s2 += bf2f(v.y & 0xffff); s3 += bf2f(v.y >> 16);
    }
  float inv = 1.0f / (float)(f * f);
  uint2 o;
  o.x = (unsigned)f2bf(s0*inv) | ((unsigned)f2bf(s1*inv) << 16);
  o.y = (unsigned)f2bf(s2*inv) | ((unsigned)f2bf(s3*inv) << 16);
  us* db = dst + (size_t)b * per * K_DIM;
  *(uint2*)(db + (size_t)rem * K_DIM + l * 4) = o;
}

// ---- fused GEMM + tap extraction ---------------------------------------------------
// Per block: 128 pixels (m-rows) x one n-chunk of one level. Computes C-subtiles via
// MFMA; epilogue extracts C-values that fall inside each pixel's 10x10 window and
// scatter-stores them (fp32) into taps[(b*4+lvl)*4096 + m][128] (slot = dy*10+dx).
// Unwritten slots remain 0 from the memset = reference's zero padding.
__global__ __launch_bounds__(256) void k_corr_taps(
    const us* __restrict__ A,
    const us* __restrict__ B0, const us* __restrict__ B1,
    const us* __restrict__ B2, const us* __restrict__ B3,
    const float* __restrict__ cc, float* __restrict__ taps){
  __shared__ __align__(16) us As[4096];
  __shared__ __align__(16) us Bs[4096];
  __shared__ unsigned meta[128];
  int bx = blockIdx.x, b = blockIdx.z, m0 = blockIdx.y * 128;
  int lvl, ntiles, n0c;
  const us* B;
  if (bx < 8)       { lvl = 0; B = B0; ntiles = 4; n0c = bx * 512; }
  else if (bx < 10) { lvl = 1; B = B1; ntiles = 4; n0c = (bx - 8) * 512; }
  else if (bx == 10){ lvl = 2; B = B2; ntiles = 2; n0c = 0; }
  else              { lvl = 3; B = B3; ntiles = 1; n0c = 0; }
  int wl = 64 >> lvl, lsh = 6 - lvl, N = wl * wl;
  float inv = 1.0f / (float)(1 << lvl);
  int t = threadIdx.x;

  if (t < 128){
    int m = m0 + t;
    float cx = cc[(size_t)b * 8192 + m];
    float cy = cc[(size_t)b * 8192 + 4096 + m];
    int px0 = (int)floorf(cx * inv) - 4;
    int py0 = (int)floorf(cy * inv) - 4;
    meta[t] = ((unsigned)(py0 + 8) << 16) | (unsigned)(px0 + 8);
  }
  // meta ordered vs all uses by the k-loop's first __syncthreads()

  const us* Ab = A + (size_t)b * M_DIM * K_DIM;
  const us* Bb = B + (size_t)b * N * K_DIM;
  float* tb = taps + (size_t)(b * 4 + lvl) * 4096 * 128;
  int wave = t >> 6, lane = t & 63;
  int wm = (wave >> 1) * 64, wn = (wave & 1) * 64;
  int srow = t >> 2, scol = (t & 3) * 8;
  int fr = lane & 15, fk = (lane >> 4) * 8;
  int cr = (lane >> 4) * 4, ccol = lane & 15;
  const us* ga0 = Ab + (size_t)(m0 + srow) * K_DIM + scol;
  const us* ga1 = ga0 + (size_t)64 * K_DIM;

  for (int tile = 0; tile < ntiles; ++tile){
    int n0 = n0c + tile * 128;
    int nr0 = n0 + srow;      if (nr0 > N - 1) nr0 = N - 1;
    int nr1 = n0 + srow + 64; if (nr1 > N - 1) nr1 = N - 1;
    const us* gb0 = Bb + (size_t)nr0 * K_DIM + scol;
    const us* gb1 = Bb + (size_t)nr1 * K_DIM + scol;

    f32x4 acc[4][4];
#pragma unroll
    for (int i = 0; i < 4; i++)
#pragma unroll
      for (int j = 0; j < 4; j++) acc[i][j] = (f32x4){0.f, 0.f, 0.f, 0.f};

    for (int kt = 0; kt < K_DIM; kt += 32){
      __syncthreads();
      gld16(ga0 + kt, As + t * 8);
      gld16(ga1 + kt, As + t * 8 + 2048);
      gld16(gb0 + kt, Bs + t * 8);
      gld16(gb1 + kt, Bs + t * 8 + 2048);
      asm volatile("s_waitcnt vmcnt(0)" ::: "memory");
      __syncthreads();
      bf16x8 af[4], bfv[4];
#pragma unroll
      for (int i = 0; i < 4; i++)
        af[i] = *(const bf16x8*)(As + (wm + i*16 + fr) * 32 + fk);
#pragma unroll
      for (int j = 0; j < 4; j++)
        bfv[j] = *(const bf16x8*)(Bs + (wn + j*16 + fr) * 32 + fk);
#pragma unroll
      for (int i = 0; i < 4; i++)
#pragma unroll
        for (int j = 0; j < 4; j++)
          acc[i][j] = __builtin_amdgcn_mfma_f32_16x16x32_bf16(af[i], bfv[j], acc[i][j], 0, 0, 0);
    }

    // extraction epilogue (C fragment layout proven in r4's store):
    // row = wm+i*16+cr+r, col = n0+wn+j*16+ccol, value = acc[i][j][r]
#pragma unroll
    for (int i = 0; i < 4; i++){
#pragma unroll
      for (int r = 0; r < 4; r++){
        int lrow = wm + i*16 + cr + r;
        unsigned mv = meta[lrow];
        int px0 = (int)(mv & 0xffffu) - 8;
        int py0 = (int)(mv >> 16) - 8;
        float* pb = tb + (size_t)(m0 + lrow) * 128;
#pragma unroll
        for (int j = 0; j < 4; j++){
          int col = n0 + wn + j*16 + ccol;
          int y2 = col >> lsh, x2 = col & (wl - 1);
          int dy = y2 - py0, dx = x2 - px0;
          if ((unsigned)dy < 10u && (unsigned)dx < 10u && col < N)
            pb[dy * 10 + dx] = acc[i][j][r];
        }
      }
    }
    // next tile's staging is fenced by the k-loop's leading __syncthreads()
  }
}

// ---- combine: bilinear over dense taps, fully coalesced ----------------------------
__global__ __launch_bounds__(256) void k_combine(
    const float* __restrict__ taps, const float* __restrict__ cc,
    float* __restrict__ out){
  __shared__ float T[128 * 129];
  int m0 = blockIdx.x * 128, b = blockIdx.y, lvl = blockIdx.z;
  int t = threadIdx.x;
  const float* src = taps + ((size_t)(b * 4 + lvl) * 4096 + m0) * 128;
  for (int k = t; k < 16384; k += 256)
    T[(k >> 7) * 129 + (k & 127)] = src[k];
  __syncthreads();

  int px = t & 127, half = t >> 7;      // wave-uniform half (waves 0,1 vs 2,3)
  int m = m0 + px;
  float inv = 1.0f / (float)(1 << lvl);
  float cx = cc[(size_t)b * 8192 + m];
  float cy = cc[(size_t)b * 8192 + 4096 + m];
  float xs = cx * inv, ys = cy * inv;
  float fx = xs - floorf(xs), fy = ys - floorf(ys);
  float wx1 = fx, wx0 = 1.0f - fx, wy1 = fy, wy0 = 1.0f - fy;
  const float* Tp = &T[px * 129];
  size_t ob = ((size_t)b * 324 + lvl * 81) * 4096 + m;
  int o_lo = half ? 41 : 0, o_hi = half ? 81 : 41;
#pragma unroll
  for (int a = 0; a < 9; a++)
#pragma unroll
    for (int d = 0; d < 9; d++){
      int o = a * 9 + d;
      if (o >= o_lo && o < o_hi){
        float s = wy0 * (wx0 * Tp[d*10 + a]     + wx1 * Tp[d*10 + a + 1])
                + wy1 * (wx0 * Tp[(d+1)*10 + a] + wx1 * Tp[(d+1)*10 + a + 1]);
        out[ob + (size_t)o * 4096] = s;
      }
    }
}

extern "C" void kernel_launch(void* const* d_in, const int* in_sizes, int n_in,
                              void* d_out, int out_size, void* d_ws, size_t ws_size,
                              hipStream_t stream){
  (void)in_sizes; (void)n_in; (void)out_size; (void)ws_size;
  const float* f1 = (const float*)d_in[0];
  const float* f2 = (const float*)d_in[1];
  const float* cc = (const float*)d_in[2];
  float* out = (float*)d_out;
  char* ws = (char*)d_ws;
  us* A  = (us*)(ws + 0);          //  4 MB  f1^T bf16 (scaled 1/16)
  us* B0 = (us*)(ws + 4194304);    //  4 MB  f2^T bf16
  us* B1 = (us*)(ws + 8388608);    //  1 MB
  us* B2 = (us*)(ws + 9437184);    //  256 KB
  us* B3 = (us*)(ws + 9699328);    //  64 KB
  float* taps = (float*)(ws + 9764864);   // 16 MB  [b*4+lvl][4096][128] fp32

  k_transpose_cast<<<dim3(64, 4, 4), dim3(256), 0, stream>>>(f1, f2, A, B0);
  k_pool_all<<<dim3(672), dim3(256), 0, stream>>>(B0, B1, B2, B3);
  hipMemsetAsync(taps, 0, (size_t)2 * 4 * 4096 * 128 * 4, stream);
  k_corr_taps<<<dim3(12, 32, 2), dim3(256), 0, stream>>>(A, B0, B1, B2, B3, cc, taps);
  k_combine<<<dim3(32, 2, 4), dim3(256), 0, stream>>>(taps, cc, out);
}

// Round 6
// 159.755 us; speedup vs baseline: 1.0288x; 1.0288x over previous
//
#include <hip/hip_runtime.h>
#include <stdint.h>

#define M_DIM 4096
#define K_DIM 256

typedef unsigned short us;
typedef __attribute__((ext_vector_type(8))) short bf16x8;
typedef __attribute__((ext_vector_type(4))) float f32x4;

static __device__ __forceinline__ float bf2f(unsigned int u){
  unsigned int x = u << 16; float f;
  __builtin_memcpy(&f, &x, 4); return f;
}
static __device__ __forceinline__ us f2bf(float f){
  unsigned int x; __builtin_memcpy(&x, &f, 4);
  unsigned int r = x + 0x7fffu + ((x >> 16) & 1u);
  return (us)(r >> 16);
}
static __device__ __forceinline__ void gld16(const void* g, void* l){
  __builtin_amdgcn_global_load_lds(
      (const __attribute__((address_space(1))) unsigned int*)g,
      (__attribute__((address_space(3))) unsigned int*)l, 16, 0, 0);
}

// ---- transpose+cast: [b,256,4096] f32 -> [b,4096,256] bf16, both fmaps one launch --
__global__ void k_transpose_cast(const float* __restrict__ f1,
                                 const float* __restrict__ f2,
                                 us* __restrict__ A, us* __restrict__ B0){
  __shared__ float lds[64][65];
  int z = blockIdx.z;           // 0..3 : b = z&1, which = z>>1
  int b = z & 1, which = z >> 1;
  const float* in = which ? f2 : f1;
  us* out = which ? B0 : A;
  float scale = which ? 1.0f : 0.0625f;   // fold 1/sqrt(256) into A
  int c0 = blockIdx.y * 64, m0 = blockIdx.x * 64;
  const float* ib = in + (size_t)b * K_DIM * M_DIM;
  us* ob = out + (size_t)b * M_DIM * K_DIM;
  int t = threadIdx.x, r = t >> 6, j = t & 63;
#pragma unroll
  for (int k = 0; k < 16; k++)
    lds[r + k*4][j] = ib[(size_t)(c0 + r + k*4) * M_DIM + m0 + j];
  __syncthreads();
#pragma unroll
  for (int k = 0; k < 16; k++)
    ob[(size_t)(m0 + r + k*4) * K_DIM + c0 + j] = f2bf(lds[j][r + k*4] * scale);
}

// ---- pools: B1 (2x2), B2 (4x4), B3 (8x8) all directly from B0, one launch ----------
__global__ void k_pool_all(const us* __restrict__ B0, us* __restrict__ B1,
                           us* __restrict__ B2, us* __restrict__ B3){
  int bid = blockIdx.x;
  us* dst; int wd, f;
  if (bid < 512)      { dst = B1; wd = 32; f = 2; }
  else if (bid < 640) { bid -= 512; dst = B2; wd = 16; f = 4; }
  else                { bid -= 640; dst = B3; wd = 8;  f = 8; }
  int t = threadIdx.x;
  int idx = bid * 4 + (t >> 6);
  int l = t & 63;
  int per = wd * wd;
  int b = idx / per, rem = idx - b * per;
  int y = rem / wd, x = rem - y * wd;
  const us* sb = B0 + (size_t)b * 4096 * K_DIM;
  float s0 = 0, s1 = 0, s2 = 0, s3 = 0;
  for (int dy = 0; dy < f; dy++)
    for (int dx = 0; dx < f; dx++){
      size_t off = ((size_t)(f*y + dy) * 64 + (f*x + dx)) * K_DIM + l * 4;
      uint2 v = *(const uint2*)(sb + off);
      s0 += bf2f(v.x & 0xffff); s1 += bf2f(v.x >> 16);
      s2 += bf2f(v.y & 0xffff); s3 += bf2f(v.y >> 16);
    }
  float inv = 1.0f / (float)(f * f);
  uint2 o;
  o.x = (unsigned)f2bf(s0*inv) | ((unsigned)f2bf(s1*inv) << 16);
  o.y = (unsigned)f2bf(s2*inv) | ((unsigned)f2bf(s3*inv) << 16);
  us* db = dst + (size_t)b * per * K_DIM;
  *(uint2*)(db + (size_t)rem * K_DIM + l * 4) = o;
}

// ---- fused GEMM + tap extraction, flat grid (one 128x128 tile per block) -----------
// Epilogue scatter-stores C-values inside each pixel's 10x10 window (fp32) into
// taps[(b*4+lvl)*4096 + m][128], slot = dy*10+dx. Invalid slots are masked to zero
// later in k_combine (no memset needed).
__global__ __launch_bounds__(256) void k_corr_taps(
    const us* __restrict__ A,
    const us* __restrict__ B0, const us* __restrict__ B1,
    const us* __restrict__ B2, const us* __restrict__ B3,
    const float* __restrict__ cc, float* __restrict__ taps){
  __shared__ __align__(16) us As[4096];
  __shared__ __align__(16) us Bs[4096];
  __shared__ unsigned meta[128];
  int bx = blockIdx.x, b = blockIdx.z, m0 = blockIdx.y * 128;
  int lvl, n0;
  const us* B;
  if (bx < 32)      { lvl = 0; B = B0; n0 = bx * 128; }
  else if (bx < 40) { lvl = 1; B = B1; n0 = (bx - 32) * 128; }
  else if (bx < 42) { lvl = 2; B = B2; n0 = (bx - 40) * 128; }
  else              { lvl = 3; B = B3; n0 = 0; }
  int wl = 64 >> lvl, lsh = 6 - lvl, N = wl * wl;
  float inv = 1.0f / (float)(1 << lvl);
  int t = threadIdx.x;

  if (t < 128){
    int m = m0 + t;
    float cx = cc[(size_t)b * 8192 + m];
    float cy = cc[(size_t)b * 8192 + 4096 + m];
    int px0 = (int)floorf(cx * inv) - 4;
    int py0 = (int)floorf(cy * inv) - 4;
    meta[t] = ((unsigned)(py0 + 8) << 16) | (unsigned)(px0 + 8);
  }
  // meta ordered vs uses by the k-loop's first __syncthreads()

  const us* Ab = A + (size_t)b * M_DIM * K_DIM;
  const us* Bb = B + (size_t)b * N * K_DIM;
  float* tb = taps + (size_t)(b * 4 + lvl) * 4096 * 128;
  int wave = t >> 6, lane = t & 63;
  int wm = (wave >> 1) * 64, wn = (wave & 1) * 64;
  int srow = t >> 2, scol = (t & 3) * 8;
  int fr = lane & 15, fk = (lane >> 4) * 8;
  int cr = (lane >> 4) * 4, ccol = lane & 15;
  int nr0 = n0 + srow;      if (nr0 > N - 1) nr0 = N - 1;
  int nr1 = n0 + srow + 64; if (nr1 > N - 1) nr1 = N - 1;
  const us* ga0 = Ab + (size_t)(m0 + srow) * K_DIM + scol;
  const us* ga1 = ga0 + (size_t)64 * K_DIM;
  const us* gb0 = Bb + (size_t)nr0 * K_DIM + scol;
  const us* gb1 = Bb + (size_t)nr1 * K_DIM + scol;

  f32x4 acc[4][4];
#pragma unroll
  for (int i = 0; i < 4; i++)
#pragma unroll
    for (int j = 0; j < 4; j++) acc[i][j] = (f32x4){0.f, 0.f, 0.f, 0.f};

  for (int kt = 0; kt < K_DIM; kt += 32){
    __syncthreads();
    gld16(ga0 + kt, As + t * 8);
    gld16(ga1 + kt, As + t * 8 + 2048);
    gld16(gb0 + kt, Bs + t * 8);
    gld16(gb1 + kt, Bs + t * 8 + 2048);
    asm volatile("s_waitcnt vmcnt(0)" ::: "memory");
    __syncthreads();
    bf16x8 af[4], bfv[4];
#pragma unroll
    for (int i = 0; i < 4; i++)
      af[i] = *(const bf16x8*)(As + (wm + i*16 + fr) * 32 + fk);
#pragma unroll
    for (int j = 0; j < 4; j++)
      bfv[j] = *(const bf16x8*)(Bs + (wn + j*16 + fr) * 32 + fk);
#pragma unroll
    for (int i = 0; i < 4; i++)
#pragma unroll
      for (int j = 0; j < 4; j++)
        acc[i][j] = __builtin_amdgcn_mfma_f32_16x16x32_bf16(af[i], bfv[j], acc[i][j], 0, 0, 0);
  }

  // extraction epilogue: (y2,x2) per j are invariant over (i,r) -> hoist.
  int y2j[4], x2j[4]; bool cokj[4];
#pragma unroll
  for (int j = 0; j < 4; j++){
    int col = n0 + wn + j*16 + ccol;
    y2j[j] = col >> lsh; x2j[j] = col & (wl - 1); cokj[j] = col < N;
  }
#pragma unroll
  for (int i = 0; i < 4; i++){
#pragma unroll
    for (int r = 0; r < 4; r++){
      int lrow = wm + i*16 + cr + r;
      unsigned mv = meta[lrow];
      int px0 = (int)(mv & 0xffffu) - 8;
      int py0 = (int)(mv >> 16) - 8;
      float* pb = tb + (size_t)(m0 + lrow) * 128;
#pragma unroll
      for (int j = 0; j < 4; j++){
        int dy = y2j[j] - py0, dx = x2j[j] - px0;
        if (cokj[j] && (unsigned)dy < 10u && (unsigned)dx < 10u)
          pb[dy * 10 + dx] = acc[i][j][r];
      }
    }
  }
}

// ---- combine: bilinear over dense taps; masks invalid/unwritten slots itself -------
__global__ __launch_bounds__(256) void k_combine(
    const float* __restrict__ taps, const float* __restrict__ cc,
    float* __restrict__ out){
  __shared__ float T[128 * 129];
  __shared__ unsigned meta[128];
  int m0 = blockIdx.x * 128, b = blockIdx.y, lvl = blockIdx.z;
  int t = threadIdx.x;
  int wl = 64 >> lvl;
  float inv = 1.0f / (float)(1 << lvl);

  if (t < 128){
    int m = m0 + t;
    float cx = cc[(size_t)b * 8192 + m];
    float cy = cc[(size_t)b * 8192 + 4096 + m];
    int px0 = (int)floorf(cx * inv) - 4;
    int py0 = (int)floorf(cy * inv) - 4;
    meta[t] = ((unsigned)(py0 + 8) << 16) | (unsigned)(px0 + 8);
  }
  __syncthreads();

  const float* src = taps + ((size_t)(b * 4 + lvl) * 4096 + m0) * 128;
  int slot = t & 127;
  if (slot < 100){
    int dy = slot / 10, dx = slot - dy * 10;
#pragma unroll
    for (int it = 0; it < 64; it++){
      int p = (t >> 7) + 2 * it;
      unsigned mv = meta[p];
      int px0 = (int)(mv & 0xffffu) - 8;
      int py0 = (int)(mv >> 16) - 8;
      bool ok = ((unsigned)(py0 + dy) < (unsigned)wl) &&
                ((unsigned)(px0 + dx) < (unsigned)wl);
      T[p * 129 + slot] = ok ? src[(size_t)p * 128 + slot] : 0.0f;
    }
  }
  __syncthreads();

  int px = t & 127, half = t >> 7;      // wave-uniform half
  int m = m0 + px;
  float cx = cc[(size_t)b * 8192 + m];
  float cy = cc[(size_t)b * 8192 + 4096 + m];
  float xs = cx * inv, ys = cy * inv;
  float fx = xs - floorf(xs), fy = ys - floorf(ys);
  float wx1 = fx, wx0 = 1.0f - fx, wy1 = fy, wy0 = 1.0f - fy;
  const float* Tp = &T[px * 129];
  size_t ob = ((size_t)b * 324 + lvl * 81) * 4096 + m;
  int o_lo = half ? 41 : 0, o_hi = half ? 81 : 41;
#pragma unroll
  for (int a = 0; a < 9; a++)
#pragma unroll
    for (int d = 0; d < 9; d++){
      int o = a * 9 + d;
      if (o >= o_lo && o < o_hi){
        float s = wy0 * (wx0 * Tp[d*10 + a]     + wx1 * Tp[d*10 + a + 1])
                + wy1 * (wx0 * Tp[(d+1)*10 + a] + wx1 * Tp[(d+1)*10 + a + 1]);
        out[ob + (size_t)o * 4096] = s;
      }
    }
}

extern "C" void kernel_launch(void* const* d_in, const int* in_sizes, int n_in,
                              void* d_out, int out_size, void* d_ws, size_t ws_size,
                              hipStream_t stream){
  (void)in_sizes; (void)n_in; (void)out_size; (void)ws_size;
  const float* f1 = (const float*)d_in[0];
  const float* f2 = (const float*)d_in[1];
  const float* cc = (const float*)d_in[2];
  float* out = (float*)d_out;
  char* ws = (char*)d_ws;
  us* A  = (us*)(ws + 0);          //  4 MB  f1^T bf16 (scaled 1/16)
  us* B0 = (us*)(ws + 4194304);    //  4 MB  f2^T bf16
  us* B1 = (us*)(ws + 8388608);    //  1 MB
  us* B2 = (us*)(ws + 9437184);    //  256 KB
  us* B3 = (us*)(ws + 9699328);    //  64 KB
  float* taps = (float*)(ws + 9764864);   // 16 MB  [b*4+lvl][4096][128] fp32

  k_transpose_cast<<<dim3(64, 4, 4), dim3(256), 0, stream>>>(f1, f2, A, B0);
  k_pool_all<<<dim3(672), dim3(256), 0, stream>>>(B0, B1, B2, B3);
  k_corr_taps<<<dim3(43, 32, 2), dim3(256), 0, stream>>>(A, B0, B1, B2, B3, cc, taps);
  k_combine<<<dim3(32, 2, 4), dim3(256), 0, stream>>>(taps, cc, out);
}